// Round 1
// 134.099 us; speedup vs baseline: 1.0062x; 1.0062x over previous
//
#include <hip/hip_runtime.h>
#include <stdint.h>
#include <stddef.h>

// Problem constants: V=50000, D=256, S=128, B=64
#define DD 256
#define SS 128
#define BB 64

typedef __bf16 bf16x8 __attribute__((ext_vector_type(8)));
typedef float  f32x4  __attribute__((ext_vector_type(4)));
typedef unsigned int u32x4 __attribute__((ext_vector_type(4)));
typedef unsigned int u32x2 __attribute__((ext_vector_type(2)));

// LDS tile layout: [col][s], stride 136 bf16 (272 B, 16B-aligned rows).
#define LSTRIDE 136
#define BUFSZ   (128 * LSTRIDE)

// Packed f32 pair -> bf16 pair. Native casts let the compiler emit
// v_cvt_pk_bf16_f32 (RNE, same numerics as the old manual round).
__device__ __forceinline__ unsigned pk2bf(float x, float y) {
    __bf16 lo = (__bf16)x;
    __bf16 hi = (__bf16)y;
    unsigned short ul = __builtin_bit_cast(unsigned short, lo);
    unsigned short uh = __builtin_bit_cast(unsigned short, hi);
    return (unsigned)ul | ((unsigned)uh << 16);
}

// Gather 4 rows x 16B per thread (one 16B column chunk of 4 consecutive s-rows).
__device__ __forceinline__ void issue_loads(const float* __restrict__ src, const int4 q,
                                            int cl, f32x4 v[4]) {
    v[0] = *(const f32x4*)(src + (size_t)q.x * DD + cl);
    v[1] = *(const f32x4*)(src + (size_t)q.y * DD + cl);
    v[2] = *(const f32x4*)(src + (size_t)q.z * DD + cl);
    v[3] = *(const f32x4*)(src + (size_t)q.w * DD + cl);
}

// Scale rows, convert to bf16 (packed), write transposed [col][s] as u32x2.
__device__ __forceinline__ void cvt_write(unsigned short* __restrict__ dst, const f32x4 scl,
                                          int s0, int cll, f32x4 v[4]) {
    f32x4 a = v[0] * scl[0];
    f32x4 b = v[1] * scl[1];
    f32x4 c = v[2] * scl[2];
    f32x4 d = v[3] * scl[3];
    #pragma unroll
    for (int j = 0; j < 4; ++j) {
        u32x2 pk;
        pk.x = pk2bf(a[j], b[j]);
        pk.y = pk2bf(c[j], d[j]);
        *(u32x2*)&dst[(cll + j) * LSTRIDE + s0] = pk;
    }
}

// One K-step (32 wide) for 2 of the 4 di-tiles of a wave's 64x32 output pair.
// B-fragments are loaded once per K-step (DI0==0) and reused by DI0==2.
// real += aR*bR + aI*bI ; imag += aI*bR - aR*bI (via sign-flipped aR).
template <int KS, int DI0>
__device__ __forceinline__ void mfma_part(const unsigned short* __restrict__ s,
                                          bf16x8 bR[2], bf16x8 bI[2],
                                          int wr, int wc, int m, int kg,
                                          f32x4 accR[4][2], f32x4 accI[4][2]) {
    const int k0 = KS * 32 + kg * 8;
    const unsigned short* pRw = s;
    const unsigned short* pIw = s + BUFSZ;
    const unsigned short* pR  = s + 2 * BUFSZ;
    const unsigned short* pI  = s + 3 * BUFSZ;
    if (DI0 == 0) {
        #pragma unroll
        for (int t = 0; t < 2; ++t) {
            const int rb = (wc * 32 + t * 16 + m) * LSTRIDE + k0;
            bR[t] = *(const bf16x8*)(pR + rb);
            bI[t] = *(const bf16x8*)(pI + rb);
        }
    }
    #pragma unroll
    for (int dd = 0; dd < 2; ++dd) {
        const int di = DI0 + dd;
        const int ra = (wr * 64 + di * 16 + m) * LSTRIDE + k0;
        bf16x8 aR = *(const bf16x8*)(pRw + ra);
        bf16x8 aI = *(const bf16x8*)(pIw + ra);
        u32x4 raw = __builtin_bit_cast(u32x4, aR) ^ 0x80008000u;
        bf16x8 aRn = __builtin_bit_cast(bf16x8, raw);
        #pragma unroll
        for (int ei = 0; ei < 2; ++ei) {
            accR[di][ei] = __builtin_amdgcn_mfma_f32_16x16x32_bf16(aR,  bR[ei], accR[di][ei], 0, 0, 0);
            accR[di][ei] = __builtin_amdgcn_mfma_f32_16x16x32_bf16(aI,  bI[ei], accR[di][ei], 0, 0, 0);
            accI[di][ei] = __builtin_amdgcn_mfma_f32_16x16x32_bf16(aI,  bR[ei], accI[di][ei], 0, 0, 0);
            accI[di][ei] = __builtin_amdgcn_mfma_f32_16x16x32_bf16(aRn, bI[ei], accI[di][ei], 0, 0, 0);
        }
    }
}

// Block = (batch, 128x128 quadrant), 512 threads = 8 waves (2 waves/SIMD for TLP).
// Buffers: 0=wR(d) 1=w*pos*C(d) 2=R(e) 3=pos*C(e).
// Pipelined: stage k-half0 -> barrier -> {gather k-half1 || MFMA ks=0,1} -> barrier -> ks=2,3.
__global__ __launch_bounds__(512, 2)
void cmp_density_kernel(const int*   __restrict__ questions,
                        const float* __restrict__ q_position,
                        const float* __restrict__ word_emb,
                        const float* __restrict__ cmp_emb,
                        const float* __restrict__ weighted_q,
                        float*       __restrict__ out)
{
    __shared__ __align__(16) unsigned short s16[4 * BUFSZ];   // 139,264 B -> 1 block/CU

    const int tid = threadIdx.x;
    const int bx  = blockIdx.x;
    const int b   = bx >> 2;
    const int td  = (bx >> 1) & 1;
    const int te  = bx & 1;

    // Staging roles: 512 threads cover 16 s-groups x 32 column chunks.
    const int sg  = tid & 15;              // s-group of 4 rows
    const int cg  = (tid >> 4) & 15;       // col chunk (low)
    const int hb  = tid >> 8;              // col chunk (high half)
    const int cll = 4 * (cg + 16 * hb);    // column within 128-wide half, [0,128)

    // Compute roles: 8 waves tile the 128x128 quadrant as 2x4 of 64x32.
    const int lane = tid & 63;
    const int wv   = tid >> 6;
    const int wr   = wv >> 2;
    const int wc   = wv & 3;
    const int m    = lane & 15;
    const int kg   = lane >> 4;

    // Metadata, both k-halves, direct from global (16B vector loads).
    const int4  q0 = *(const int4*)(questions + b * SS + 4 * sg);
    const int4  q1 = *(const int4*)(questions + b * SS + 64 + 4 * sg);
    const f32x4 p0 = *(const f32x4*)(q_position + b * SS + 4 * sg);
    const f32x4 p1 = *(const f32x4*)(q_position + b * SS + 64 + 4 * sg);
    const f32x4 w0 = *(const f32x4*)(weighted_q + 4 * sg);
    const f32x4 w1 = *(const f32x4*)(weighted_q + 64 + 4 * sg);
    const f32x4 ones = {1.f, 1.f, 1.f, 1.f};
    const f32x4 wp0 = w0 * p0;
    const f32x4 wp1 = w1 * p1;

    f32x4 vA[4], vB[4];

    // ---- stage k-half 0 (s in [0,64)) ----
    issue_loads(word_emb, q0, td * 128 + cll, vA);
    issue_loads(cmp_emb,  q0, td * 128 + cll, vB);
    cvt_write(s16 + 0 * BUFSZ, w0,  4 * sg, cll, vA);
    cvt_write(s16 + 1 * BUFSZ, wp0, 4 * sg, cll, vB);
    issue_loads(word_emb, q0, te * 128 + cll, vA);
    issue_loads(cmp_emb,  q0, te * 128 + cll, vB);
    cvt_write(s16 + 2 * BUFSZ, ones, 4 * sg, cll, vA);
    cvt_write(s16 + 3 * BUFSZ, p0,   4 * sg, cll, vB);
    __syncthreads();

    f32x4 accR[4][2] = {};
    f32x4 accI[4][2] = {};
    bf16x8 bR[2], bI[2];

    // ---- overlap: gather k-half 1 (s in [64,128)) while computing ks=0,1 ----
    issue_loads(word_emb, q1, td * 128 + cll, vA);
    mfma_part<0, 0>(s16, bR, bI, wr, wc, m, kg, accR, accI);
    cvt_write(s16 + 0 * BUFSZ, w1, 64 + 4 * sg, cll, vA);
    issue_loads(cmp_emb, q1, td * 128 + cll, vB);
    mfma_part<0, 2>(s16, bR, bI, wr, wc, m, kg, accR, accI);
    cvt_write(s16 + 1 * BUFSZ, wp1, 64 + 4 * sg, cll, vB);
    issue_loads(word_emb, q1, te * 128 + cll, vA);
    mfma_part<1, 0>(s16, bR, bI, wr, wc, m, kg, accR, accI);
    cvt_write(s16 + 2 * BUFSZ, ones, 64 + 4 * sg, cll, vA);
    issue_loads(cmp_emb, q1, te * 128 + cll, vB);
    mfma_part<1, 2>(s16, bR, bI, wr, wc, m, kg, accR, accI);
    cvt_write(s16 + 3 * BUFSZ, p1, 64 + 4 * sg, cll, vB);
    __syncthreads();

    // ---- remaining K on half 1 ----
    mfma_part<2, 0>(s16, bR, bI, wr, wc, m, kg, accR, accI);
    mfma_part<2, 2>(s16, bR, bI, wr, wc, m, kg, accR, accI);
    mfma_part<3, 0>(s16, bR, bI, wr, wc, m, kg, accR, accI);
    mfma_part<3, 2>(s16, bR, bI, wr, wc, m, kg, accR, accI);

    // ---- epilogue: C/D layout col=lane&15, row=(lane>>4)*4+reg ----
    float* outR = out + (size_t)b * DD * DD;
    float* outI = out + (size_t)BB * DD * DD + (size_t)b * DD * DD;
    const int d0 = td * 128 + wr * 64;
    const int e0 = te * 128 + wc * 32;
    #pragma unroll
    for (int di = 0; di < 4; ++di) {
        #pragma unroll
        for (int ei = 0; ei < 2; ++ei) {
            const int e = e0 + ei * 16 + m;
            #pragma unroll
            for (int r = 0; r < 4; ++r) {
                const int d = d0 + di * 16 + kg * 4 + r;
                outR[d * DD + e] = accR[di][ei][r];
                outI[d * DD + e] = accI[di][ei][r];
            }
        }
    }
}

extern "C" void kernel_launch(void* const* d_in, const int* in_sizes, int n_in,
                              void* d_out, int out_size, void* d_ws, size_t ws_size,
                              hipStream_t stream) {
    const int*   questions  = (const int*)d_in[0];
    const float* q_position = (const float*)d_in[1];
    const float* word_emb   = (const float*)d_in[2];
    const float* cmp_emb    = (const float*)d_in[3];
    const float* weighted_q = (const float*)d_in[4];
    float* out = (float*)d_out;
    (void)in_sizes; (void)n_in; (void)d_ws; (void)ws_size; (void)out_size;

    cmp_density_kernel<<<dim3(BB * 4), dim3(512), 0, stream>>>(
        questions, q_position, word_emb, cmp_emb, weighted_q, out);
}

// Round 3
// 133.608 us; speedup vs baseline: 1.0099x; 1.0037x over previous
//
#include <hip/hip_runtime.h>
#include <stdint.h>
#include <stddef.h>

// Problem constants: V=50000, D=256, S=128, B=64
#define DD 256
#define SS 128
#define BB 64

typedef __bf16 bf16x8 __attribute__((ext_vector_type(8)));
typedef float  f32x4  __attribute__((ext_vector_type(4)));
typedef unsigned int u32x4 __attribute__((ext_vector_type(4)));
typedef unsigned int u32x2 __attribute__((ext_vector_type(2)));

// LDS tile layout: [col][s], stride 136 bf16 (272 B, 16B-aligned rows).
#define LSTRIDE 136
#define BUFSZ   (128 * LSTRIDE)

// Packed f32 pair -> bf16 pair. Native casts let the compiler emit
// v_cvt_pk_bf16_f32 (RNE).
__device__ __forceinline__ unsigned pk2bf(float x, float y) {
    __bf16 lo = (__bf16)x;
    __bf16 hi = (__bf16)y;
    unsigned short ul = __builtin_bit_cast(unsigned short, lo);
    unsigned short uh = __builtin_bit_cast(unsigned short, hi);
    return (unsigned)ul | ((unsigned)uh << 16);
}

// Gather 4 rows x 16B per thread (one 16B column chunk of 4 consecutive s-rows).
// Wave-level: 16 rows x 64 B contiguous per instruction.
__device__ __forceinline__ void issue_loads(const float* __restrict__ src, const int4 q,
                                            int cl, f32x4 v[4]) {
    v[0] = *(const f32x4*)(src + (size_t)q.x * DD + cl);
    v[1] = *(const f32x4*)(src + (size_t)q.y * DD + cl);
    v[2] = *(const f32x4*)(src + (size_t)q.z * DD + cl);
    v[3] = *(const f32x4*)(src + (size_t)q.w * DD + cl);
}

// Scale rows, convert to bf16 (packed), write transposed [col][s] as u32x2.
__device__ __forceinline__ void cvt_write(unsigned short* __restrict__ dst, const f32x4 scl,
                                          int s0, int cll, f32x4 v[4]) {
    f32x4 a = v[0] * scl[0];
    f32x4 b = v[1] * scl[1];
    f32x4 c = v[2] * scl[2];
    f32x4 d = v[3] * scl[3];
    #pragma unroll
    for (int j = 0; j < 4; ++j) {
        u32x2 pk;
        pk.x = pk2bf(a[j], b[j]);
        pk.y = pk2bf(c[j], d[j]);
        *(u32x2*)&dst[(cll + j) * LSTRIDE + s0] = pk;
    }
}

// One K-step (32 wide) for 2 of the 4 di-tiles of a wave's 64x32 output pair.
// B-fragments are loaded once per K-step (DI0==0) and reused by DI0==2.
// real += aR*bR + aI*bI ; imag += aI*bR - aR*bI (via sign-flipped aR).
template <int KS, int DI0>
__device__ __forceinline__ void mfma_part(const unsigned short* __restrict__ s,
                                          bf16x8 bR[2], bf16x8 bI[2],
                                          int wr, int wc, int m, int kg,
                                          f32x4 accR[4][2], f32x4 accI[4][2]) {
    const int k0 = KS * 32 + kg * 8;
    const unsigned short* pRw = s;
    const unsigned short* pIw = s + BUFSZ;
    const unsigned short* pR  = s + 2 * BUFSZ;
    const unsigned short* pI  = s + 3 * BUFSZ;
    if (DI0 == 0) {
        #pragma unroll
        for (int t = 0; t < 2; ++t) {
            const int rb = (wc * 32 + t * 16 + m) * LSTRIDE + k0;
            bR[t] = *(const bf16x8*)(pR + rb);
            bI[t] = *(const bf16x8*)(pI + rb);
        }
    }
    #pragma unroll
    for (int dd = 0; dd < 2; ++dd) {
        const int di = DI0 + dd;
        const int ra = (wr * 64 + di * 16 + m) * LSTRIDE + k0;
        bf16x8 aR = *(const bf16x8*)(pRw + ra);
        bf16x8 aI = *(const bf16x8*)(pIw + ra);
        u32x4 raw = __builtin_bit_cast(u32x4, aR) ^ 0x80008000u;
        bf16x8 aRn = __builtin_bit_cast(bf16x8, raw);
        #pragma unroll
        for (int ei = 0; ei < 2; ++ei) {
            accR[di][ei] = __builtin_amdgcn_mfma_f32_16x16x32_bf16(aR,  bR[ei], accR[di][ei], 0, 0, 0);
            accR[di][ei] = __builtin_amdgcn_mfma_f32_16x16x32_bf16(aI,  bI[ei], accR[di][ei], 0, 0, 0);
            accI[di][ei] = __builtin_amdgcn_mfma_f32_16x16x32_bf16(aI,  bR[ei], accI[di][ei], 0, 0, 0);
            accI[di][ei] = __builtin_amdgcn_mfma_f32_16x16x32_bf16(aRn, bI[ei], accI[di][ei], 0, 0, 0);
        }
    }
}

// Block = (batch, 128x128 quadrant), 512 threads = 8 waves (2 waves/SIMD for TLP).
// Buffers: 0=wR(d) 1=w*pos*C(d) 2=R(e) 3=pos*C(e).
// All 32 global load groups issued up-front (single exposed HBM latency; poison
// fills evict L3 every iter so gathers are cold). Diagonal blocks (td==te)
// dedup their gathers: buffers 2/3 are the same rows+cols as 0/1.
__global__ __launch_bounds__(512, 2)
void cmp_density_kernel(const int*   __restrict__ questions,
                        const float* __restrict__ q_position,
                        const float* __restrict__ word_emb,
                        const float* __restrict__ cmp_emb,
                        const float* __restrict__ weighted_q,
                        float*       __restrict__ out)
{
    __shared__ __align__(16) unsigned short s16[4 * BUFSZ];   // 139,264 B -> 1 block/CU

    const int tid = threadIdx.x;
    const int bx  = blockIdx.x;
    const int b   = bx >> 2;
    const int td  = (bx >> 1) & 1;
    const int te  = bx & 1;
    const bool diag = (td == te);

    // Staging roles: 512 threads cover 16 s-groups x 32 column chunks.
    const int sg  = tid & 15;              // s-group of 4 rows
    const int cg  = (tid >> 4) & 15;       // col chunk (low)
    const int hb  = tid >> 8;              // col chunk (high half)
    const int cll = 4 * (cg + 16 * hb);    // column within 128-wide half, [0,128)

    // Compute roles: 8 waves tile the 128x128 quadrant as 2x4 of 64x32.
    const int lane = tid & 63;
    const int wv   = tid >> 6;
    const int wr   = wv >> 2;
    const int wc   = wv & 3;
    const int m    = lane & 15;
    const int kg   = lane >> 4;

    // Metadata, both k-halves, direct from global (16B vector loads).
    const int4  q0 = *(const int4*)(questions + b * SS + 4 * sg);
    const int4  q1 = *(const int4*)(questions + b * SS + 64 + 4 * sg);
    const f32x4 p0 = *(const f32x4*)(q_position + b * SS + 4 * sg);
    const f32x4 p1 = *(const f32x4*)(q_position + b * SS + 64 + 4 * sg);
    const f32x4 w0 = *(const f32x4*)(weighted_q + 4 * sg);
    const f32x4 w1 = *(const f32x4*)(weighted_q + 64 + 4 * sg);
    const f32x4 ones = {1.f, 1.f, 1.f, 1.f};
    const f32x4 wp0 = w0 * p0;
    const f32x4 wp1 = w1 * p1;

    // ---- issue ALL gathers up front (one exposed HBM round-trip) ----
    f32x4 rA0[4], rB0[4], rA1[4], rB1[4];   // k-half 0: word/cmp x d-half/e-half
    f32x4 sA0[4], sB0[4], sA1[4], sB1[4];   // k-half 1
    issue_loads(word_emb, q0, td * 128 + cll, rA0);
    issue_loads(cmp_emb,  q0, td * 128 + cll, rB0);
    if (!diag) {
        issue_loads(word_emb, q0, te * 128 + cll, rA1);
        issue_loads(cmp_emb,  q0, te * 128 + cll, rB1);
    }
    issue_loads(word_emb, q1, td * 128 + cll, sA0);
    issue_loads(cmp_emb,  q1, td * 128 + cll, sB0);
    if (!diag) {
        issue_loads(word_emb, q1, te * 128 + cll, sA1);
        issue_loads(cmp_emb,  q1, te * 128 + cll, sB1);
    }

    // ---- stage k-half 0 (s in [0,64)) ----
    cvt_write(s16 + 0 * BUFSZ, w0,  4 * sg, cll, rA0);
    cvt_write(s16 + 1 * BUFSZ, wp0, 4 * sg, cll, rB0);
    if (diag) {
        cvt_write(s16 + 2 * BUFSZ, ones, 4 * sg, cll, rA0);
        cvt_write(s16 + 3 * BUFSZ, p0,   4 * sg, cll, rB0);
    } else {
        cvt_write(s16 + 2 * BUFSZ, ones, 4 * sg, cll, rA1);
        cvt_write(s16 + 3 * BUFSZ, p0,   4 * sg, cll, rB1);
    }
    __syncthreads();

    f32x4 accR[4][2] = {};
    f32x4 accI[4][2] = {};
    bf16x8 bR[2], bI[2];

    // ---- overlap: stage k-half 1 (regs already loaded) while computing ks=0,1 ----
    mfma_part<0, 0>(s16, bR, bI, wr, wc, m, kg, accR, accI);
    cvt_write(s16 + 0 * BUFSZ, w1, 64 + 4 * sg, cll, sA0);
    mfma_part<0, 2>(s16, bR, bI, wr, wc, m, kg, accR, accI);
    cvt_write(s16 + 1 * BUFSZ, wp1, 64 + 4 * sg, cll, sB0);
    mfma_part<1, 0>(s16, bR, bI, wr, wc, m, kg, accR, accI);
    if (diag) {
        cvt_write(s16 + 2 * BUFSZ, ones, 64 + 4 * sg, cll, sA0);
    } else {
        cvt_write(s16 + 2 * BUFSZ, ones, 64 + 4 * sg, cll, sA1);
    }
    mfma_part<1, 2>(s16, bR, bI, wr, wc, m, kg, accR, accI);
    if (diag) {
        cvt_write(s16 + 3 * BUFSZ, p1, 64 + 4 * sg, cll, sB0);
    } else {
        cvt_write(s16 + 3 * BUFSZ, p1, 64 + 4 * sg, cll, sB1);
    }
    __syncthreads();

    // ---- remaining K on half 1 ----
    mfma_part<2, 0>(s16, bR, bI, wr, wc, m, kg, accR, accI);
    mfma_part<2, 2>(s16, bR, bI, wr, wc, m, kg, accR, accI);
    mfma_part<3, 0>(s16, bR, bI, wr, wc, m, kg, accR, accI);
    mfma_part<3, 2>(s16, bR, bI, wr, wc, m, kg, accR, accI);

    // ---- epilogue: C/D layout col=lane&15, row=(lane>>4)*4+reg ----
    float* outR = out + (size_t)b * DD * DD;
    float* outI = out + (size_t)BB * DD * DD + (size_t)b * DD * DD;
    const int d0 = td * 128 + wr * 64;
    const int e0 = te * 128 + wc * 32;
    #pragma unroll
    for (int di = 0; di < 4; ++di) {
        #pragma unroll
        for (int ei = 0; ei < 2; ++ei) {
            const int e = e0 + ei * 16 + m;
            #pragma unroll
            for (int r = 0; r < 4; ++r) {
                const int d = d0 + di * 16 + kg * 4 + r;
                outR[d * DD + e] = accR[di][ei][r];
                outI[d * DD + e] = accI[di][ei][r];
            }
        }
    }
}

extern "C" void kernel_launch(void* const* d_in, const int* in_sizes, int n_in,
                              void* d_out, int out_size, void* d_ws, size_t ws_size,
                              hipStream_t stream) {
    const int*   questions  = (const int*)d_in[0];
    const float* q_position = (const float*)d_in[1];
    const float* word_emb   = (const float*)d_in[2];
    const float* cmp_emb    = (const float*)d_in[3];
    const float* weighted_q = (const float*)d_in[4];
    float* out = (float*)d_out;
    (void)in_sizes; (void)n_in; (void)d_ws; (void)ws_size; (void)out_size;

    cmp_density_kernel<<<dim3(BB * 4), dim3(512), 0, stream>>>(
        questions, q_position, word_emb, cmp_emb, weighted_q, out);
}